// Round 2
// baseline (193.024 us; speedup 1.0000x reference)
//
#include <hip/hip_runtime.h>

// Post_Prob_GS: B=8, N=256 points, grid 128x128 (HW=16384), stride 4.
// out[b, n, hw] = softmax over n of likelihood; n==256 is the background term.
//
// Structure: prepass packs per-point coefficients (expanded quadratic form,
// pre-scaled by log2(e)) into d_ws; main kernel evaluates
//   likeK = KA*gx^2 + KB*gx*gy + KD*gy^2 + cx*gx + cy*gy + c0     (5 FMAs)
// with wave-uniform coefficient loads (scalar s_load path, no LDS).

#define HWC 16384
#define NPTS 256
#define NBATCH 8

#define K_LOG2E 1.4426950408889634f
// log2e*(-0.5*100^2) + log2(0.15)
#define BK_CONST (-7216.2121700389835f)

__global__ __launch_bounds__(256) void prep_kernel(
    const float* __restrict__ scale,     // (B,N,2)
    const float* __restrict__ rotation,  // (B,N,1)
    const float* __restrict__ points,    // (B,N,2)
    float4* __restrict__ P)              // (B*N) x 2 float4
{
    const int i = blockIdx.x * 256 + threadIdx.x;   // 0..2047 = b*256+n
    if (i >= NBATCH * NPTS) return;

    float sx = fminf(fmaxf(32.0f * scale[i * 2 + 0], 2.0f), 100.0f);
    float sy = fminf(fmaxf(32.0f * scale[i * 2 + 1], 2.0f), 100.0f);
    float sx2 = sx * sx, sy2 = sy * sy;

    float th = rotation[i];
    float s, c;
    sincosf(th, &s, &c);
    float cov_a = c * c * sx2 + s * s * sy2;
    float cov_b = c * s * (sx2 - sy2);
    float cov_d = s * s * sx2 + c * c * sy2;
    float det  = sx2 * sy2;
    float rdet = 1.0f / det;

    // z = -0.5*(inv_a dx^2 + 2 inv_b dx dy + inv_d dy^2); scale all by log2e
    float KA = -0.5f * K_LOG2E * (cov_d * rdet);      // coef dx^2
    float KB =         K_LOG2E * (cov_b * rdet);      // coef dx*dy (= -inv_b*K... sign: -1*(-cov_b/det))
    float KD = -0.5f * K_LOG2E * (cov_a * rdet);      // coef dy^2

    float px = points[i * 2 + 0];
    float py = points[i * 2 + 1];

    // expand around grid vars: zK = KA*gx^2 + KB*gx*gy + KD*gy^2 + cx*gx + cy*gy + cz
    float cx = -(2.0f * KA * px + KB * py);
    float cy = -(KB * px + 2.0f * KD * py);
    float cz = KA * px * px + KB * px * py + KD * py * py;

    float l2det = log2f(det);
    float HLK = -0.5f * l2det;          // log2-domain -0.5*log(det) term

    P[i * 2 + 0] = make_float4(KA, KB, KD, cx);
    P[i * 2 + 1] = make_float4(cy, cz + HLK, HLK, l2det);
}

__global__ __launch_bounds__(256) void post_prob_kernel(
    const float4* __restrict__ P,   // packed coeffs in ws
    float* __restrict__ out)        // (B, 257, HW)
{
    const int b  = blockIdx.x >> 6;                       // 64 blocks per batch
    const int hw = ((blockIdx.x & 63) << 8) + threadIdx.x;

    const float gx = (float)((hw & 127) * 4 + 2);
    const float gy = (float)((hw >> 7) * 4 + 2);
    const float gxx = gx * gx, gxy = gx * gy, gyy = gy * gy;

    const float4* __restrict__ Pb = P + (size_t)b * NPTS * 2;

    // ---- pass 1: max of likeK; track logdet of first-argmax over zK ----
    float m   = -INFINITY;
    float bz  = -INFINITY;
    float bld = 0.0f;
    #pragma unroll 8
    for (int n = 0; n < NPTS; ++n) {
        float4 q0 = Pb[n * 2 + 0];
        float4 q1 = Pb[n * 2 + 1];
        float like = fmaf(q0.x, gxx, fmaf(q0.y, gxy, fmaf(q0.z, gyy,
                     fmaf(q0.w, gx,  fmaf(q1.x, gy, q1.y)))));
        float z = like - q1.z;
        m = fmaxf(m, like);
        bool gt = z > bz;                 // strict > : first max wins
        bz  = gt ? z    : bz;
        bld = gt ? q1.w : bld;
    }
    const float bk = BK_CONST - bz - bld;
    m = fmaxf(m, bk);

    // ---- pass 2: sum of exp2 ----
    float sum = 0.0f;
    #pragma unroll 8
    for (int n = 0; n < NPTS; ++n) {
        float4 q0 = Pb[n * 2 + 0];
        float4 q1 = Pb[n * 2 + 1];
        float like = fmaf(q0.x, gxx, fmaf(q0.y, gxy, fmaf(q0.z, gyy,
                     fmaf(q0.w, gx,  fmaf(q1.x, gy, q1.y)))));
        sum += exp2f(like - m);
    }
    sum += exp2f(bk - m);
    const float m2 = m + log2f(sum);      // fold 1/sum into the exponent

    // ---- pass 3: normalized writes (lanes contiguous in hw) ----
    float* __restrict__ outb = out + (size_t)b * 257 * HWC + hw;
    #pragma unroll 8
    for (int n = 0; n < NPTS; ++n) {
        float4 q0 = Pb[n * 2 + 0];
        float4 q1 = Pb[n * 2 + 1];
        float like = fmaf(q0.x, gxx, fmaf(q0.y, gxy, fmaf(q0.z, gyy,
                     fmaf(q0.w, gx,  fmaf(q1.x, gy, q1.y)))));
        outb[(size_t)n * HWC] = exp2f(like - m2);
    }
    outb[(size_t)256 * HWC] = exp2f(bk - m2);
}

extern "C" void kernel_launch(void* const* d_in, const int* in_sizes, int n_in,
                              void* d_out, int out_size, void* d_ws, size_t ws_size,
                              hipStream_t stream) {
    const float* scale    = (const float*)d_in[0];
    const float* rotation = (const float*)d_in[1];
    const float* points   = (const float*)d_in[2];
    float* out = (float*)d_out;
    float4* P  = (float4*)d_ws;
    (void)in_sizes; (void)n_in; (void)out_size; (void)ws_size;

    prep_kernel<<<dim3(NBATCH), dim3(256), 0, stream>>>(scale, rotation, points, P);
    post_prob_kernel<<<dim3(NBATCH * (HWC / 256)), dim3(256), 0, stream>>>(P, out);
}